// Round 3
// baseline (720.255 us; speedup 1.0000x reference)
//
#include <hip/hip_runtime.h>

#define N_NODES 50000
#define N_EDGES 800000
#define HID 64
#define LAYERS 4

typedef unsigned short u16;
typedef __attribute__((ext_vector_type(8))) __bf16 bf16x8;
typedef __attribute__((ext_vector_type(8))) unsigned short u16x8;
typedef __attribute__((ext_vector_type(4))) float f32x4;

__device__ __forceinline__ u16 f2bf(float f) {
  unsigned u = __builtin_bit_cast(unsigned, f);
  u += 0x7fffu + ((u >> 16) & 1u);   // RNE
  return (u16)(u >> 16);
}
__device__ __forceinline__ float bf2f(u16 s) {
  return __builtin_bit_cast(float, ((unsigned)s) << 16);
}

// ---------------- weight prep -------------------------------------------------
// W1x: [L][64][128] bf16 (k: 0-63 h_src, 64-127 h_dst)
// Wvx: [L][3][64] f32   (We @ W1c — the rank-3 edge_vec term, kept fp32)
// b1x: [L][64] f32      (b1 + be@W1c)
// W2x/M1x/M2x: transposed bf16
__global__ void prep_kernel(const float* __restrict__ ew1, const float* __restrict__ eb1,
                            const float* __restrict__ ew2, const float* __restrict__ nw1,
                            const float* __restrict__ nw2,
                            const float* __restrict__ edge_enc_w, const float* __restrict__ edge_enc_b,
                            u16* W1x, float* Wvx, float* b1x, u16* W2x, u16* M1x, u16* M2x) {
  int idx = blockIdx.x * 256 + threadIdx.x;
  const int szA = LAYERS * 64 * 128;
  const int szV = LAYERS * 3 * 64;
  const int szB = LAYERS * 64;
  const int szC = LAYERS * 64 * 64;
  const int szD = LAYERS * 64 * 128;
  const int szE = LAYERS * 64 * 64;
  if (idx < szA) {
    int l = idx / (64 * 128); int r = idx % (64 * 128);
    int f = r / 128; int k = r % 128;
    W1x[idx] = f2bf(ew1[(l * 192 + k) * 64 + f]);
    return;
  }
  idx -= szA;
  if (idx < szV) {
    int l = idx / 192, r = idx % 192, a = r / 64, f = r % 64;
    float s = 0.f;
    for (int m = 0; m < 64; ++m) s += edge_enc_w[a * 64 + m] * ew1[(l * 192 + 128 + m) * 64 + f];
    Wvx[idx] = s;
    return;
  }
  idx -= szV;
  if (idx < szB) {
    int l = idx / 64, f = idx % 64;
    float s = eb1[l * 64 + f];
    for (int m = 0; m < 64; ++m) s += edge_enc_b[m] * ew1[(l * 192 + 128 + m) * 64 + f];
    b1x[idx] = s;
    return;
  }
  idx -= szB;
  if (idx < szC) { int l = idx / 4096, r = idx % 4096, f = r / 64, k = r % 64;
    W2x[idx] = f2bf(ew2[(l * 64 + k) * 64 + f]); return; }
  idx -= szC;
  if (idx < szD) { int l = idx / 8192, r = idx % 8192, f = r / 128, k = r % 128;
    M1x[idx] = f2bf(nw1[(l * 128 + k) * 64 + f]); return; }
  idx -= szD;
  if (idx < szE) { int l = idx / 4096, r = idx % 4096, f = r / 64, k = r % 64;
    M2x[idx] = f2bf(nw2[(l * 64 + k) * 64 + f]); return; }
}

// ---------------- encoder ----------------------------------------------------
__global__ __launch_bounds__(256) void encode_kernel(const float* __restrict__ nf,
                                                     const float* __restrict__ enc_w,
                                                     const float* __restrict__ enc_b,
                                                     u16* __restrict__ h) {
  int idx = blockIdx.x * 256 + threadIdx.x;
  if (idx >= N_NODES * HID) return;
  int n = idx >> 6, j = idx & 63;
  float s = enc_b[j]
          + nf[n * 3 + 0] * enc_w[j]
          + nf[n * 3 + 1] * enc_w[64 + j]
          + nf[n * 3 + 2] * enc_w[128 + j];
  h[idx] = f2bf(s);
}

// ---------------- counting sort of edges by dst ------------------------------
__global__ __launch_bounds__(256) void hist_kernel(const int* __restrict__ dstA,
                                                   int* __restrict__ cnt) {
  int idx = blockIdx.x * 256 + threadIdx.x;
  if (idx < N_EDGES) atomicAdd(&cnt[dstA[idx]], 1);
}

// hierarchical exclusive scan: 25 blocks x 2048 elems, then scan partials, then add
#define SCAN_NBLK 25
__global__ __launch_bounds__(256) void scan1_kernel(const int* __restrict__ cnt,
                                                    int* __restrict__ offs,
                                                    int* __restrict__ partials) {
  __shared__ int sm[2048];
  __shared__ int ws2[256];
  int t = threadIdx.x, b = blockIdx.x;
  int base = b * 2048;
#pragma unroll
  for (int i = 0; i < 8; ++i) {
    int idx = base + i * 256 + t;
    sm[i * 256 + t] = (idx < N_NODES) ? cnt[idx] : 0;
  }
  __syncthreads();
  int loc[8]; int s = 0;
#pragma unroll
  for (int i = 0; i < 8; ++i) { loc[i] = s; s += sm[t * 8 + i]; }
  ws2[t] = s;
  __syncthreads();
  for (int off = 1; off < 256; off <<= 1) {
    int u = (t >= off) ? ws2[t - off] : 0;
    __syncthreads();
    ws2[t] += u;
    __syncthreads();
  }
  int tbase = (t > 0) ? ws2[t - 1] : 0;
  if (t == 255) partials[b] = ws2[255];
#pragma unroll
  for (int i = 0; i < 8; ++i) {
    int idx = base + t * 8 + i;
    if (idx < N_NODES) offs[idx] = tbase + loc[i];
  }
}

__global__ void scan2_kernel(int* partials) {
  if (threadIdx.x == 0) {
    int s = 0;
    for (int i = 0; i < SCAN_NBLK; ++i) { int v = partials[i]; partials[i] = s; s += v; }
  }
}

__global__ __launch_bounds__(256) void scan3_kernel(int* __restrict__ offs,
                                                    const int* __restrict__ partials) {
  int idx = blockIdx.x * 256 + threadIdx.x;
  if (idx < N_NODES) offs[idx] += partials[idx >> 11];
}

__global__ __launch_bounds__(256) void scatter_kernel(const int* __restrict__ dstA,
                                                      const int* __restrict__ offs,
                                                      int* __restrict__ cursor,
                                                      int* __restrict__ perm) {
  int idx = blockIdx.x * 256 + threadIdx.x;
  if (idx >= N_EDGES) return;
  int d = dstA[idx];
  int p = atomicAdd(&cursor[d], 1);
  perm[offs[d] + p] = idx;
}

// ---------------- edge MLP + segmented reduction + scatter-add ---------------
// A-fragments for GEMM1 gathered DIRECTLY from global (L1/L2-resident h rows);
// no Xs staging buffer. K=128 (v-term moved to a VALU epilogue).
// LDS ~27 KB -> 6 blocks/CU.
__global__ __launch_bounds__(256, 6) void edge_kernel(
    const u16* __restrict__ h, const int* __restrict__ ei,
    const int* __restrict__ perm,
    const float* __restrict__ pos,
    const u16* __restrict__ W1x, const float* __restrict__ Wvx,
    const float* __restrict__ b1x,
    const u16* __restrict__ W2x, const float* __restrict__ eb2,
    float* __restrict__ agg, int layer) {
  __shared__ u16 Hs[64 * 72];       // 9216 B: hidden [edge][64] pad->72
  __shared__ float Fs[64 * 66];     // 16896 B: GEMM2 fp32 out, stride 66 (2-way only)
  __shared__ int sSrc[64], sDst[64];
  __shared__ u16 sV[3][64];         // edge_vec as bf16 (matches prior accuracy)
  int t = threadIdx.x;
  int lane = t & 63, wv = t >> 6;
  int n16 = lane & 15, quad = lane >> 4;
  int F = wv * 16;

  // weight B-fragments in registers
  bf16x8 B1[4], B2[2];
  {
    const u16* p = W1x + (size_t)(layer * 64 + F + n16) * 128 + quad * 8;
#pragma unroll
    for (int ks = 0; ks < 4; ++ks) B1[ks] = __builtin_bit_cast(bf16x8, *(const u16x8*)(p + ks * 32));
    const u16* q = W2x + (size_t)(layer * 64 + F + n16) * 64 + quad * 8;
#pragma unroll
    for (int ks = 0; ks < 2; ++ks) B2[ks] = __builtin_bit_cast(bf16x8, *(const u16x8*)(q + ks * 32));
  }
  float bias1 = b1x[layer * 64 + F + n16];
  float wv0 = Wvx[(layer * 3 + 0) * 64 + F + n16];
  float wv1 = Wvx[(layer * 3 + 1) * 64 + F + n16];
  float wv2 = Wvx[(layer * 3 + 2) * 64 + F + n16];
  float bias2r = eb2[layer * 64 + lane];

  int e0 = blockIdx.x * 64;
  if (t < 64) {
    int ge = perm[e0 + t];
    int s = ei[ge], d = ei[N_EDGES + ge];
    sSrc[t] = s; sDst[t] = d;
    sV[0][t] = f2bf(pos[d * 3 + 0] - pos[s * 3 + 0]);
    sV[1][t] = f2bf(pos[d * 3 + 1] - pos[s * 3 + 1]);
    sV[2][t] = f2bf(pos[d * 3 + 2] - pos[s * 3 + 2]);
  }
  __syncthreads();

  // GEMM1: direct-gather A fragments; K = 128
  f32x4 acc[4];
#pragma unroll
  for (int m = 0; m < 4; ++m) acc[m] = (f32x4){0.f, 0.f, 0.f, 0.f};
#pragma unroll
  for (int m = 0; m < 4; ++m) {
    int e = m * 16 + n16;
    const u16* hs = h + (size_t)sSrc[e] * 64 + quad * 8;
    const u16* hd = h + (size_t)sDst[e] * 64 + quad * 8;
    bf16x8 a0 = __builtin_bit_cast(bf16x8, *(const u16x8*)(hs));
    bf16x8 a1 = __builtin_bit_cast(bf16x8, *(const u16x8*)(hs + 32));
    bf16x8 a2 = __builtin_bit_cast(bf16x8, *(const u16x8*)(hd));
    bf16x8 a3 = __builtin_bit_cast(bf16x8, *(const u16x8*)(hd + 32));
    acc[m] = __builtin_amdgcn_mfma_f32_16x16x32_bf16(a0, B1[0], acc[m], 0, 0, 0);
    acc[m] = __builtin_amdgcn_mfma_f32_16x16x32_bf16(a1, B1[1], acc[m], 0, 0, 0);
    acc[m] = __builtin_amdgcn_mfma_f32_16x16x32_bf16(a2, B1[2], acc[m], 0, 0, 0);
    acc[m] = __builtin_amdgcn_mfma_f32_16x16x32_bf16(a3, B1[3], acc[m], 0, 0, 0);
  }
  // epilogue 1: v-term + bias + relu -> bf16 -> Hs
#pragma unroll
  for (int m = 0; m < 4; ++m) {
#pragma unroll
    for (int r = 0; r < 4; ++r) {
      int e = m * 16 + quad * 4 + r;
      float v = acc[m][r] + bias1
              + bf2f(sV[0][e]) * wv0 + bf2f(sV[1][e]) * wv1 + bf2f(sV[2][e]) * wv2;
      v = v > 0.f ? v : 0.f;
      Hs[e * 72 + F + n16] = f2bf(v);
    }
  }
  __syncthreads();

  // GEMM2 -> Fs (fp32)
#pragma unroll
  for (int m = 0; m < 4; ++m) {
    const u16* hp = Hs + (m * 16 + n16) * 72 + quad * 8;
    f32x4 c = (f32x4){0.f, 0.f, 0.f, 0.f};
#pragma unroll
    for (int ks = 0; ks < 2; ++ks) {
      bf16x8 a = __builtin_bit_cast(bf16x8, *(const u16x8*)(hp + ks * 32));
      c = __builtin_amdgcn_mfma_f32_16x16x32_bf16(a, B2[ks], c, 0, 0, 0);
    }
#pragma unroll
    for (int r = 0; r < 4; ++r) {
      int e = m * 16 + quad * 4 + r;
      Fs[e * 66 + F + n16] = c[r];
    }
  }
  __syncthreads();

  // segmented reduction: wave wv scans edges [wv*16, wv*16+16), lane = feature
  {
    float sum = 0.f;
    int cur = sDst[wv * 16];
#pragma unroll
    for (int i = 0; i < 16; ++i) {
      int e = wv * 16 + i;
      int d = sDst[e];
      if (d != cur) {
        atomicAdd(&agg[(size_t)cur * 64 + lane], sum);
        sum = 0.f;
        cur = d;
      }
      sum += Fs[e * 66 + lane] + bias2r;
    }
    atomicAdd(&agg[(size_t)cur * 64 + lane], sum);
  }
}

// ---------------- node MLP ---------------------------------------------------
__global__ __launch_bounds__(256) void node_kernel(
    const u16* __restrict__ h, const float* __restrict__ agg,
    const u16* __restrict__ M1x, const float* __restrict__ nb1,
    const u16* __restrict__ M2x, const float* __restrict__ nb2,
    u16* __restrict__ h2, int layer) {
  __shared__ u16 Xs[64 * 136];
  __shared__ u16 Hs[64 * 72];
  int t = threadIdx.x;
  int lane = t & 63, wv = t >> 6;
  int n16 = lane & 15, quad = lane >> 4;
  int F = wv * 16;

  bf16x8 B1[4], B2[2];
  {
    const u16* p = M1x + (size_t)(layer * 64 + F + n16) * 128 + quad * 8;
#pragma unroll
    for (int ks = 0; ks < 4; ++ks) B1[ks] = __builtin_bit_cast(bf16x8, *(const u16x8*)(p + ks * 32));
    const u16* q = M2x + (size_t)(layer * 64 + F + n16) * 64 + quad * 8;
#pragma unroll
    for (int ks = 0; ks < 2; ++ks) B2[ks] = __builtin_bit_cast(bf16x8, *(const u16x8*)(q + ks * 32));
  }
  float bias1 = nb1[layer * 64 + F + n16];
  float bias2 = nb2[layer * 64 + F + n16];

  int n0 = blockIdx.x * 64;
  {
    int e = t >> 2, part = t & 3;
    int gn = n0 + e;
    u16* xr = Xs + e * 136;
    if (gn < N_NODES) {
      const u16* hp = h + (size_t)gn * 64 + part * 16;
      *(u16x8*)(xr + part * 16)     = *(const u16x8*)(hp);
      *(u16x8*)(xr + part * 16 + 8) = *(const u16x8*)(hp + 8);
      const float* ap = agg + (size_t)gn * 64 + part * 16;
      u16* w = xr + 64 + part * 16;
#pragma unroll
      for (int i = 0; i < 4; ++i) {
        float4 a = *(const float4*)(ap + i * 4);
        w[i * 4 + 0] = f2bf(a.x); w[i * 4 + 1] = f2bf(a.y);
        w[i * 4 + 2] = f2bf(a.z); w[i * 4 + 3] = f2bf(a.w);
      }
    } else {
      u16x8 z = {0, 0, 0, 0, 0, 0, 0, 0};
      *(u16x8*)(xr + part * 16)          = z;
      *(u16x8*)(xr + part * 16 + 8)      = z;
      *(u16x8*)(xr + 64 + part * 16)     = z;
      *(u16x8*)(xr + 64 + part * 16 + 8) = z;
    }
  }
  __syncthreads();

  f32x4 acc[4];
#pragma unroll
  for (int m = 0; m < 4; ++m) acc[m] = (f32x4){0.f, 0.f, 0.f, 0.f};
#pragma unroll
  for (int m = 0; m < 4; ++m) {
    const u16* xp = Xs + (m * 16 + n16) * 136 + quad * 8;
#pragma unroll
    for (int ks = 0; ks < 4; ++ks) {
      bf16x8 a = __builtin_bit_cast(bf16x8, *(const u16x8*)(xp + ks * 32));
      acc[m] = __builtin_amdgcn_mfma_f32_16x16x32_bf16(a, B1[ks], acc[m], 0, 0, 0);
    }
  }
#pragma unroll
  for (int m = 0; m < 4; ++m) {
#pragma unroll
    for (int r = 0; r < 4; ++r) {
      int e = m * 16 + quad * 4 + r;
      float v = acc[m][r] + bias1;
      v = v > 0.f ? v : 0.f;
      Hs[e * 72 + F + n16] = f2bf(v);
    }
  }
  __syncthreads();

#pragma unroll
  for (int m = 0; m < 4; ++m) {
    const u16* hp = Hs + (m * 16 + n16) * 72 + quad * 8;
    f32x4 c = (f32x4){0.f, 0.f, 0.f, 0.f};
#pragma unroll
    for (int ks = 0; ks < 2; ++ks) {
      bf16x8 a = __builtin_bit_cast(bf16x8, *(const u16x8*)(hp + ks * 32));
      c = __builtin_amdgcn_mfma_f32_16x16x32_bf16(a, B2[ks], c, 0, 0, 0);
    }
#pragma unroll
    for (int r = 0; r < 4; ++r) {
      int e = m * 16 + quad * 4 + r;
      int gn = n0 + e;
      if (gn < N_NODES) h2[(size_t)gn * 64 + F + n16] = f2bf(c[r] + bias2);
    }
  }
}

// ---------------- decoder ----------------------------------------------------
__global__ __launch_bounds__(256) void decode_kernel(const u16* __restrict__ h,
                                                     const float* __restrict__ dec_w,
                                                     const float* __restrict__ dec_b,
                                                     float* __restrict__ out) {
  int t = threadIdx.x;
  int lane = t & 63, wv = t >> 6;
  int n = blockIdx.x * 4 + wv;
  float p = bf2f(h[(size_t)n * 64 + lane]) * dec_w[lane];
#pragma unroll
  for (int o = 32; o > 0; o >>= 1) p += __shfl_xor(p, o);
  if (lane == 0) out[n] = p + dec_b[0];
}

extern "C" void kernel_launch(void* const* d_in, const int* in_sizes, int n_in,
                              void* d_out, int out_size, void* d_ws, size_t ws_size,
                              hipStream_t stream) {
  const float* node_pos   = (const float*)d_in[0];
  const float* node_feat  = (const float*)d_in[1];
  const int*   edge_index = (const int*)d_in[2];
  const float* enc_w      = (const float*)d_in[3];
  const float* enc_b      = (const float*)d_in[4];
  const float* edge_enc_w = (const float*)d_in[5];
  const float* edge_enc_b = (const float*)d_in[6];
  const float* ew1        = (const float*)d_in[7];
  const float* eb1        = (const float*)d_in[8];
  const float* ew2        = (const float*)d_in[9];
  const float* eb2        = (const float*)d_in[10];
  const float* nw1        = (const float*)d_in[11];
  const float* nb1        = (const float*)d_in[12];
  const float* nw2        = (const float*)d_in[13];
  const float* nb2        = (const float*)d_in[14];
  const float* dec_w      = (const float*)d_in[15];
  const float* dec_b      = (const float*)d_in[16];
  float* out = (float*)d_out;

  char* ws = (char*)d_ws;
  size_t off = 0;
  u16*   hA  = (u16*)(ws + off);   off += (size_t)N_NODES * 64 * 2;
  u16*   hB  = (u16*)(ws + off);   off += (size_t)N_NODES * 64 * 2;
  float* agg = (float*)(ws + off); off += (size_t)N_NODES * 64 * 4;
  u16*   W1x = (u16*)(ws + off);   off += (size_t)LAYERS * 64 * 128 * 2;
  float* Wvx = (float*)(ws + off); off += (size_t)LAYERS * 3 * 64 * 4;
  float* b1x = (float*)(ws + off); off += (size_t)LAYERS * 64 * 4;
  u16*   W2x = (u16*)(ws + off);   off += (size_t)LAYERS * 64 * 64 * 2;
  u16*   M1x = (u16*)(ws + off);   off += (size_t)LAYERS * 64 * 128 * 2;
  u16*   M2x = (u16*)(ws + off);   off += (size_t)LAYERS * 64 * 64 * 2;
  int*   cnt    = (int*)(ws + off); off += (size_t)N_NODES * 4;
  int*   offs   = (int*)(ws + off); off += (size_t)N_NODES * 4;
  int*   cursor = (int*)(ws + off); off += (size_t)N_NODES * 4;
  int*   partials = (int*)(ws + off); off += 32 * 4;
  int*   perm   = (int*)(ws + off); off += (size_t)N_EDGES * 4;

  const int* dstA = edge_index + N_EDGES;

  const int prepTotal = LAYERS * (64 * 128 + 3 * 64 + 64 + 64 * 64 + 64 * 128 + 64 * 64);
  prep_kernel<<<(prepTotal + 255) / 256, 256, 0, stream>>>(
      ew1, eb1, ew2, nw1, nw2, edge_enc_w, edge_enc_b, W1x, Wvx, b1x, W2x, M1x, M2x);
  encode_kernel<<<(N_NODES * 64 + 255) / 256, 256, 0, stream>>>(node_feat, enc_w, enc_b, hA);

  // one-time counting sort of edges by dst (hierarchical scan)
  hipMemsetAsync(cnt, 0, (size_t)N_NODES * 4, stream);
  hipMemsetAsync(cursor, 0, (size_t)N_NODES * 4, stream);
  hist_kernel<<<(N_EDGES + 255) / 256, 256, 0, stream>>>(dstA, cnt);
  scan1_kernel<<<SCAN_NBLK, 256, 0, stream>>>(cnt, offs, partials);
  scan2_kernel<<<1, 64, 0, stream>>>(partials);
  scan3_kernel<<<(N_NODES + 255) / 256, 256, 0, stream>>>(offs, partials);
  scatter_kernel<<<(N_EDGES + 255) / 256, 256, 0, stream>>>(dstA, offs, cursor, perm);

  u16* hcur = hA; u16* hnext = hB;
  for (int l = 0; l < LAYERS; ++l) {
    hipMemsetAsync(agg, 0, (size_t)N_NODES * 64 * 4, stream);
    edge_kernel<<<N_EDGES / 64, 256, 0, stream>>>(hcur, edge_index, perm, node_pos,
                                                  W1x, Wvx, b1x, W2x, eb2, agg, l);
    node_kernel<<<(N_NODES + 63) / 64, 256, 0, stream>>>(hcur, agg, M1x, nb1, M2x, nb2,
                                                         hnext, l);
    u16* tmp = hcur; hcur = hnext; hnext = tmp;
  }
  decode_kernel<<<N_NODES / 4, 256, 0, stream>>>(hcur, dec_w, dec_b, out);
}